// Round 3
// baseline (241.941 us; speedup 1.0000x reference)
//
#include <hip/hip_runtime.h>

#define HEADS 16
#define HDIM 64
#define EMB 1024
#define SEQ 2048
#define NBATCH 2

typedef short short8 __attribute__((ext_vector_type(8)));
typedef float f32x4 __attribute__((ext_vector_type(4)));
typedef float f32x16 __attribute__((ext_vector_type(16)));

__device__ __forceinline__ unsigned short f2bf(float f) {
  unsigned u = __builtin_bit_cast(unsigned, f);
  u += 0x7fffu + ((u >> 16) & 1u);
  return (unsigned short)(u >> 16);
}

__device__ __forceinline__ unsigned cvtpk(float lo, float hi) {
  unsigned r;
  asm("v_cvt_pk_bf16_f32 %0, %1, %2" : "=v"(r) : "v"(lo), "v"(hi));
  return r;
}

// swap: a' = [a.lo32lanes, b.lo32lanes], b' = [a.hi32lanes, b.hi32lanes]
__device__ __forceinline__ void swap32(unsigned& a, unsigned& b) {
  asm("v_permlane32_swap_b32 %0, %1" : "+v"(a), "+v"(b));
}

// ---------------------------------------------------------------------------
// prep: Wo fp32->bf16 (b<1024), mask->bias floats (1024..1027),
//       per-64-chunk mask flags (b==1028)
// ---------------------------------------------------------------------------
__global__ __launch_bounds__(256) void prep_kernel(const float* __restrict__ src,
                                                   unsigned short* __restrict__ dst,
                                                   const int* __restrict__ mask,
                                                   float* __restrict__ biasf,
                                                   int* __restrict__ flags) {
  int b = blockIdx.x;
  int t = threadIdx.x;
  if (b < 1024) {
    int i = (b * 256 + t) * 4;
    float4 v = *(const float4*)(src + i);
    uint2 pk;
    pk.x = (unsigned)f2bf(v.x) | ((unsigned)f2bf(v.y) << 16);
    pk.y = (unsigned)f2bf(v.z) | ((unsigned)f2bf(v.w) << 16);
    *(uint2*)(dst + i) = pk;
  } else if (b < 1028) {
    int i = (b - 1024) * 1024 + t * 4;
    int4 m = *(const int4*)(mask + i);
    float4 o;
    o.x = m.x ? 0.0f : -1e30f;
    o.y = m.y ? 0.0f : -1e30f;
    o.z = m.z ? 0.0f : -1e30f;
    o.w = m.w ? 0.0f : -1e30f;
    *(float4*)(biasf + i) = o;
  } else if (t < 64) {
    // flag[j]: 1 if any zero in mask[n][tile*64..+64), j = n*32+tile
    int n = t >> 5, tile = t & 31;
    const int* mp = mask + n * SEQ + tile * 64;
    int anyz = 0;
#pragma unroll
    for (int i = 0; i < 16; ++i) {
      int4 m = *(const int4*)(mp + i * 4);
      anyz |= (!m.x) | (!m.y) | (!m.z) | (!m.w);
    }
    flags[t] = anyz;
  }
}

// ---------------------------------------------------------------------------
// Per-head projections (unchanged, verified).
// tensor 0=q (scaled), 1=k, 2=v (transposed [n][h][d][l]).
// ---------------------------------------------------------------------------
__global__ __launch_bounds__(256) void proj_kernel(
    const float* __restrict__ q_in, const float* __restrict__ k_in,
    const float* __restrict__ v_in, const float* __restrict__ Wq,
    const float* __restrict__ Wk, const float* __restrict__ Wv,
    unsigned short* __restrict__ qp, unsigned short* __restrict__ kp,
    unsigned short* __restrict__ vt, float qscale) {
  int t = threadIdx.x;
  int lb = blockIdx.x;
  int h = blockIdx.y;
  int zz = blockIdx.z;
  int tensor = zz >> 1, n = zz & 1;

  const float* x;
  const float* W;
  float scale = 1.0f;
  if (tensor == 0) { x = q_in; W = Wq; scale = qscale; }
  else if (tensor == 1) { x = k_in; W = Wk; }
  else { x = v_in; W = Wv; }

  __shared__ float Wl[64 * 64];
#pragma unroll
  for (int i = 0; i < 16; ++i) Wl[t + i * 256] = W[t + i * 256];
  __syncthreads();

  int l = lb * 256 + t;
  const float* xr = x + ((size_t)(n * SEQ + l) * HEADS + h) * HDIM;
  float xv[64];
#pragma unroll
  for (int i = 0; i < 16; ++i) {
    float4 v4 = *(const float4*)(xr + i * 4);
    xv[i * 4 + 0] = v4.x; xv[i * 4 + 1] = v4.y;
    xv[i * 4 + 2] = v4.z; xv[i * 4 + 3] = v4.w;
  }

  size_t slab = (size_t)(n * HEADS + h);
  if (tensor < 2) {
    unsigned short* outp = (tensor == 0 ? qp : kp) + (slab * SEQ + l) * HDIM;
    for (int e8 = 0; e8 < 8; ++e8) {
      float ye[8];
#pragma unroll
      for (int ei = 0; ei < 8; ++ei) {
        const float* wr = &Wl[(e8 * 8 + ei) * 64];
        float acc = 0.0f;
#pragma unroll
        for (int d4 = 0; d4 < 16; ++d4) {
          float4 w4 = *(const float4*)(wr + d4 * 4);
          acc += xv[d4 * 4 + 0] * w4.x + xv[d4 * 4 + 1] * w4.y +
                 xv[d4 * 4 + 2] * w4.z + xv[d4 * 4 + 3] * w4.w;
        }
        ye[ei] = acc * scale;
      }
      uint4 pk;
      pk.x = (unsigned)f2bf(ye[0]) | ((unsigned)f2bf(ye[1]) << 16);
      pk.y = (unsigned)f2bf(ye[2]) | ((unsigned)f2bf(ye[3]) << 16);
      pk.z = (unsigned)f2bf(ye[4]) | ((unsigned)f2bf(ye[5]) << 16);
      pk.w = (unsigned)f2bf(ye[6]) | ((unsigned)f2bf(ye[7]) << 16);
      *(uint4*)(outp + e8 * 8) = pk;
    }
  } else {
    unsigned short* outp = vt + slab * HDIM * SEQ + l;
    for (int e = 0; e < 64; ++e) {
      const float* wr = &Wl[e * 64];
      float acc = 0.0f;
#pragma unroll
      for (int d4 = 0; d4 < 16; ++d4) {
        float4 w4 = *(const float4*)(wr + d4 * 4);
        acc += xv[d4 * 4 + 0] * w4.x + xv[d4 * 4 + 1] * w4.y +
               xv[d4 * 4 + 2] * w4.z + xv[d4 * 4 + 3] * w4.w;
      }
      outp[(size_t)e * SEQ] = f2bf(acc);
    }
  }
}

// ---------------------------------------------------------------------------
// Flash attention v3: 32x32x16 MFMA, swapped QK^T, in-register softmax+P,
// permlane32_swap P redistribution, async K/V staging.
// Block = 128 thr (2 waves); wave owns 32 q-rows; KVBLK = 64.
// qp/kp: [n][h][l][d] bf16 (q pre-scaled by log2e/32), vt: [n][h][d][l] bf16.
// ---------------------------------------------------------------------------
__global__ __launch_bounds__(128) void attn_kernel(
    const unsigned short* __restrict__ qp, const unsigned short* __restrict__ kp,
    const unsigned short* __restrict__ vt, const float* __restrict__ biasf,
    const int* __restrict__ flags, unsigned short* __restrict__ ao) {
  int t = threadIdx.x;
  int w = t >> 6;
  int lane = t & 63;
  int l5 = lane & 31, hi = lane >> 5;
  int qw = blockIdx.x * 64 + w * 32;
  int h = blockIdx.y, n = blockIdx.z;
  size_t slab = (size_t)(n * HEADS + h);
  const unsigned short* Qb = qp + slab * SEQ * HDIM;
  const unsigned short* Kb = kp + slab * SEQ * HDIM;
  const unsigned short* Vb = vt + slab * (size_t)HDIM * SEQ;
  const float* biasp = biasf + n * SEQ;
  const int* flagp = flags + n * 32;

  __shared__ uint4 Kl[512];  // [64 k-rows][8 chunks], idx ^ (row&7)
  __shared__ uint4 Vl[512];  // [64 d-rows][8 chunks], idx ^ (row&7)

  // Q B-frags: lane holds Q[q=qw+l5][d = dstep*16 + hi*8 + j]
  short8 bq[4];
  {
    const unsigned short* qrow = Qb + (size_t)(qw + l5) * HDIM + hi * 8;
#pragma unroll
    for (int dstep = 0; dstep < 4; ++dstep)
      bq[dstep] = __builtin_bit_cast(short8, *(const uint4*)(qrow + dstep * 16));
  }

  f32x16 acc0 = {}, acc1 = {};
  float mrun = -1e30f, lrun = 0.0f;
  const int rsw = l5 & 7;

  // staging regs (tile kb): K row=c>>3 chunk=c&7; V identical shape
  uint4 kreg[4], vreg[4];
#pragma unroll
  for (int s = 0; s < 4; ++s) {
    int c = t + s * 128, row = c >> 3, c8 = c & 7;
    kreg[s] = *(const uint4*)(Kb + (size_t)row * HDIM + c8 * 8);
    vreg[s] = *(const uint4*)(Vb + (size_t)row * SEQ + c8 * 8);
  }

  for (int kb = 0; kb < SEQ; kb += 64) {
    // write staged tile (compiler inserts vmcnt wait on kreg/vreg)
#pragma unroll
    for (int s = 0; s < 4; ++s) {
      int c = t + s * 128, row = c >> 3, c8 = c & 7;
      int idx = (row * 8 + c8) ^ (row & 7);
      Kl[idx] = kreg[s];
      Vl[idx] = vreg[s];
    }
    __syncthreads();

    // issue next tile's loads; latency hides under compute
    if (kb + 64 < SEQ) {
      int kb2 = kb + 64;
#pragma unroll
      for (int s = 0; s < 4; ++s) {
        int c = t + s * 128, row = c >> 3, c8 = c & 7;
        kreg[s] = *(const uint4*)(Kb + (size_t)(kb2 + row) * HDIM + c8 * 8);
        vreg[s] = *(const uint4*)(Vb + (size_t)row * SEQ + kb2 + c8 * 8);
      }
    }

    // ---- QK^T: S^T[k][q]; s0 = k 0..31, s1 = k 32..63 ----
    f32x16 s0 = {}, s1 = {};
    __builtin_amdgcn_s_setprio(1);
#pragma unroll
    for (int dstep = 0; dstep < 4; ++dstep) {
      short8 kf0 = __builtin_bit_cast(short8, Kl[l5 * 8 + ((dstep * 2 + hi) ^ rsw)]);
      short8 kf1 = __builtin_bit_cast(short8, Kl[256 + l5 * 8 + ((dstep * 2 + hi) ^ rsw)]);
      s0 = __builtin_amdgcn_mfma_f32_32x32x16_bf16(kf0, bq[dstep], s0, 0, 0, 0);
      s1 = __builtin_amdgcn_mfma_f32_32x32x16_bf16(kf1, bq[dstep], s1, 0, 0, 0);
    }
    __builtin_amdgcn_s_setprio(0);

    // ---- optional mask bias (skipped when chunk fully unmasked) ----
    if (flagp[kb >> 6]) {
#pragma unroll
      for (int g = 0; g < 4; ++g) {
        f32x4 b0 = *(const f32x4*)(biasp + kb + g * 8 + hi * 4);
        f32x4 b1 = *(const f32x4*)(biasp + kb + 32 + g * 8 + hi * 4);
#pragma unroll
        for (int i = 0; i < 4; ++i) {
          s0[g * 4 + i] += b0[i];
          s1[g * 4 + i] += b1[i];
        }
      }
    }

    // ---- row max: in-lane tree over 32 + 1 shuffle ----
    float m0[8];
#pragma unroll
    for (int i = 0; i < 8; ++i)
      m0[i] = fmaxf(fmaxf(s0[i], s0[i + 8]), fmaxf(s1[i], s1[i + 8]));
    float rm = fmaxf(fmaxf(fmaxf(m0[0], m0[1]), fmaxf(m0[2], m0[3])),
                     fmaxf(fmaxf(m0[4], m0[5]), fmaxf(m0[6], m0[7])));
    rm = fmaxf(rm, __shfl_xor(rm, 32, 64));

    if (__any(rm > mrun)) {
      float mnew = fmaxf(mrun, rm);
      float rs = exp2f(mrun - mnew);
      mrun = mnew;
      lrun *= rs;
      acc0 = acc0 * rs;
      acc1 = acc1 * rs;
    }

    // ---- P = exp2(S - m) ----
    float p[32];
#pragma unroll
    for (int i = 0; i < 16; ++i) p[i] = exp2f(s0[i] - mrun);
#pragma unroll
    for (int i = 0; i < 16; ++i) p[16 + i] = exp2f(s1[i] - mrun);

    float q0[8];
#pragma unroll
    for (int i = 0; i < 8; ++i) q0[i] = (p[i] + p[i + 8]) + (p[i + 16] + p[i + 24]);
    float ps = ((q0[0] + q0[1]) + (q0[2] + q0[3])) + ((q0[4] + q0[5]) + (q0[6] + q0[7]));
    ps += __shfl_xor(ps, 32, 64);
    lrun += ps;

    // ---- pack to bf16 words + permlane32_swap into B-frags ----
    unsigned wv[16];
#pragma unroll
    for (int m = 0; m < 8; ++m) wv[m] = cvtpk(p[2 * m], p[2 * m + 1]);
#pragma unroll
    for (int m = 0; m < 8; ++m) wv[8 + m] = cvtpk(p[16 + 2 * m], p[16 + 2 * m + 1]);

    short8 pf[4];
#pragma unroll
    for (int kt = 0; kt < 2; ++kt) {
#pragma unroll
      for (int s = 0; s < 2; ++s) {
        unsigned a = wv[kt * 8 + s * 4 + 0], c = wv[kt * 8 + s * 4 + 2];
        unsigned b = wv[kt * 8 + s * 4 + 1], d = wv[kt * 8 + s * 4 + 3];
        swap32(a, c);
        swap32(b, d);
        uint4 u = {a, b, c, d};
        pf[kt * 2 + s] = __builtin_bit_cast(short8, u);
      }
    }

    // ---- PV: O^T[d][q] += V^T-frag x P-frag ----
    __builtin_amdgcn_s_setprio(1);
#pragma unroll
    for (int ks = 0; ks < 4; ++ks) {
      short8 v0 = __builtin_bit_cast(short8, Vl[l5 * 8 + ((ks * 2 + hi) ^ rsw)]);
      short8 v1 = __builtin_bit_cast(short8, Vl[256 + l5 * 8 + ((ks * 2 + hi) ^ rsw)]);
      acc0 = __builtin_amdgcn_mfma_f32_32x32x16_bf16(v0, pf[ks], acc0, 0, 0, 0);
      acc1 = __builtin_amdgcn_mfma_f32_32x32x16_bf16(v1, pf[ks], acc1, 0, 0, 0);
    }
    __builtin_amdgcn_s_setprio(0);
    __syncthreads();
  }

  // ---- epilogue: lane holds O[q=qw+l5][d = db*32 + 8g + 4hi + i] ----
  float inv = 1.0f / lrun;
  unsigned short* obase = ao + ((size_t)(n * SEQ + qw + l5)) * EMB + h * HDIM + hi * 4;
#pragma unroll
  for (int g = 0; g < 4; ++g) {
    uint2 o0, o1;
    o0.x = cvtpk(acc0[g * 4 + 0] * inv, acc0[g * 4 + 1] * inv);
    o0.y = cvtpk(acc0[g * 4 + 2] * inv, acc0[g * 4 + 3] * inv);
    o1.x = cvtpk(acc1[g * 4 + 0] * inv, acc1[g * 4 + 1] * inv);
    o1.y = cvtpk(acc1[g * 4 + 2] * inv, acc1[g * 4 + 3] * inv);
    *(uint2*)(obase + g * 8) = o0;
    *(uint2*)(obase + 32 + g * 8) = o1;
  }
}

// ---------------------------------------------------------------------------
// Out-projection (unchanged, verified).
// ---------------------------------------------------------------------------
__global__ __launch_bounds__(256) void gemm_bt_kernel(
    const unsigned short* __restrict__ A, const unsigned short* __restrict__ B,
    const float* __restrict__ bias, float* __restrict__ Cm) {
  int t = threadIdx.x;
  int lane = t & 63, w = t >> 6;
  int lr = lane & 15, lg = lane >> 4;
  int m0 = blockIdx.y * 128, n0 = blockIdx.x * 64;
  int wr = w >> 1, wc = w & 1;

  __shared__ uint4 Al[1024];
  __shared__ uint4 Bl[512];

  f32x4 zero = {0.0f, 0.0f, 0.0f, 0.0f};
  f32x4 acc[4][2];
#pragma unroll
  for (int mt = 0; mt < 4; ++mt)
#pragma unroll
    for (int nt = 0; nt < 2; ++nt) acc[mt][nt] = zero;

  for (int kt = 0; kt < EMB; kt += 64) {
    __syncthreads();
#pragma unroll
    for (int s = 0; s < 4; ++s) {
      int c = t + s * 256;
      int row = c >> 3, c16 = c & 7;
      uint4 v = *(const uint4*)(A + (size_t)(m0 + row) * EMB + kt + c16 * 8);
      Al[(row * 8 + c16) ^ (row & 7)] = v;
    }
#pragma unroll
    for (int s = 0; s < 2; ++s) {
      int c = t + s * 256;
      int row = c >> 3, c16 = c & 7;
      uint4 v = *(const uint4*)(B + (size_t)(n0 + row) * EMB + kt + c16 * 8);
      Bl[(row * 8 + c16) ^ (row & 7)] = v;
    }
    __syncthreads();
#pragma unroll
    for (int kk = 0; kk < 2; ++kk) {
      short8 af[4], bfr[2];
#pragma unroll
      for (int mt = 0; mt < 4; ++mt) {
        int row = wr * 64 + mt * 16 + lr;
        af[mt] = __builtin_bit_cast(short8, Al[(row * 8 + kk * 4 + lg) ^ (row & 7)]);
      }
#pragma unroll
      for (int nt = 0; nt < 2; ++nt) {
        int row = wc * 32 + nt * 16 + lr;
        bfr[nt] = __builtin_bit_cast(short8, Bl[(row * 8 + kk * 4 + lg) ^ (row & 7)]);
      }
#pragma unroll
      for (int mt = 0; mt < 4; ++mt)
#pragma unroll
        for (int nt = 0; nt < 2; ++nt)
          acc[mt][nt] = __builtin_amdgcn_mfma_f32_16x16x32_bf16(af[mt], bfr[nt],
                                                                acc[mt][nt], 0, 0, 0);
    }
  }

#pragma unroll
  for (int nt = 0; nt < 2; ++nt) {
    int col = n0 + wc * 32 + nt * 16 + lr;
    float bv = bias[col];
#pragma unroll
    for (int mt = 0; mt < 4; ++mt) {
#pragma unroll
      for (int i = 0; i < 4; ++i) {
        int rowm = m0 + wr * 64 + mt * 16 + lg * 4 + i;
        Cm[(size_t)rowm * EMB + col] = acc[mt][nt][i] + bv;
      }
    }
  }
}

// ---------------------------------------------------------------------------
extern "C" void kernel_launch(void* const* d_in, const int* in_sizes, int n_in,
                              void* d_out, int out_size, void* d_ws, size_t ws_size,
                              hipStream_t stream) {
  const float* values = (const float*)d_in[0];
  const float* keys   = (const float*)d_in[1];
  const float* query  = (const float*)d_in[2];
  const int*   mask   = (const int*)d_in[3];
  const float* Wv     = (const float*)d_in[4];
  const float* Wk     = (const float*)d_in[5];
  const float* Wq     = (const float*)d_in[6];
  const float* Wo     = (const float*)d_in[7];
  const float* bo     = (const float*)d_in[8];
  float* out = (float*)d_out;

  const size_t slab = (size_t)NBATCH * HEADS * SEQ * HDIM;  // 4,194,304 elems
  unsigned short* qp  = (unsigned short*)d_ws;
  unsigned short* kp  = qp + slab;
  unsigned short* vt  = kp + slab;
  unsigned short* ao  = vt + slab;
  unsigned short* wob = ao + slab;
  float* biasf = (float*)(wob + (size_t)EMB * EMB);
  int* flags = (int*)(biasf + NBATCH * SEQ);

  float qscale = 1.4426950408889634f / 32.0f;

  prep_kernel<<<dim3(1029), 256, 0, stream>>>(Wo, wob, mask, biasf, flags);
  proj_kernel<<<dim3(SEQ / 256, HEADS, 6), 256, 0, stream>>>(
      query, keys, values, Wq, Wk, Wv, qp, kp, vt, qscale);
  attn_kernel<<<dim3(SEQ / 64, HEADS, NBATCH), 128, 0, stream>>>(qp, kp, vt, biasf,
                                                                 flags, ao);
  gemm_bt_kernel<<<dim3(EMB / 64, (NBATCH * SEQ) / 128), 256, 0, stream>>>(ao, wob, bo, out);
}

// Round 4
// 170.937 us; speedup vs baseline: 1.4154x; 1.4154x over previous
//
#include <hip/hip_runtime.h>

#define HEADS 16
#define HDIM 64
#define EMB 1024
#define SEQ 2048
#define NBATCH 2

typedef short short8 __attribute__((ext_vector_type(8)));
typedef float f32x4 __attribute__((ext_vector_type(4)));
typedef float f32x16 __attribute__((ext_vector_type(16)));

__device__ __forceinline__ unsigned short f2bf(float f) {
  unsigned u = __builtin_bit_cast(unsigned, f);
  u += 0x7fffu + ((u >> 16) & 1u);
  return (unsigned short)(u >> 16);
}

__device__ __forceinline__ unsigned cvtpk(float lo, float hi) {
  unsigned r;
  asm("v_cvt_pk_bf16_f32 %0, %1, %2" : "=v"(r) : "v"(lo), "v"(hi));
  return r;
}

// a' = [a.lo32lanes, b.lo32lanes], b' = [a.hi32lanes, b.hi32lanes]
__device__ __forceinline__ void swap32(unsigned& a, unsigned& b) {
  asm("v_permlane32_swap_b32 %0, %1" : "+v"(a), "+v"(b));
}

// ---------------------------------------------------------------------------
// prep: Wo fp32->bf16 (b<1024), mask->bias floats (1024..1027),
//       per-64-chunk mask flags (b==1028)
// ---------------------------------------------------------------------------
__global__ __launch_bounds__(256) void prep_kernel(const float* __restrict__ src,
                                                   unsigned short* __restrict__ dst,
                                                   const int* __restrict__ mask,
                                                   float* __restrict__ biasf,
                                                   int* __restrict__ flags) {
  int b = blockIdx.x;
  int t = threadIdx.x;
  if (b < 1024) {
    int i = (b * 256 + t) * 4;
    float4 v = *(const float4*)(src + i);
    uint2 pk;
    pk.x = (unsigned)f2bf(v.x) | ((unsigned)f2bf(v.y) << 16);
    pk.y = (unsigned)f2bf(v.z) | ((unsigned)f2bf(v.w) << 16);
    *(uint2*)(dst + i) = pk;
  } else if (b < 1028) {
    int i = (b - 1024) * 1024 + t * 4;
    int4 m = *(const int4*)(mask + i);
    float4 o;
    o.x = m.x ? 0.0f : -1e30f;
    o.y = m.y ? 0.0f : -1e30f;
    o.z = m.z ? 0.0f : -1e30f;
    o.w = m.w ? 0.0f : -1e30f;
    *(float4*)(biasf + i) = o;
  } else if (t < 64) {
    int n = t >> 5, tile = t & 31;
    const int* mp = mask + n * SEQ + tile * 64;
    int anyz = 0;
#pragma unroll
    for (int i = 0; i < 16; ++i) {
      int4 m = *(const int4*)(mp + i * 4);
      anyz |= (!m.x) | (!m.y) | (!m.z) | (!m.w);
    }
    flags[t] = anyz;
  }
}

// ---------------------------------------------------------------------------
// Per-head projections (unchanged, verified).
// ---------------------------------------------------------------------------
__global__ __launch_bounds__(256) void proj_kernel(
    const float* __restrict__ q_in, const float* __restrict__ k_in,
    const float* __restrict__ v_in, const float* __restrict__ Wq,
    const float* __restrict__ Wk, const float* __restrict__ Wv,
    unsigned short* __restrict__ qp, unsigned short* __restrict__ kp,
    unsigned short* __restrict__ vt, float qscale) {
  int t = threadIdx.x;
  int lb = blockIdx.x;
  int h = blockIdx.y;
  int zz = blockIdx.z;
  int tensor = zz >> 1, n = zz & 1;

  const float* x;
  const float* W;
  float scale = 1.0f;
  if (tensor == 0) { x = q_in; W = Wq; scale = qscale; }
  else if (tensor == 1) { x = k_in; W = Wk; }
  else { x = v_in; W = Wv; }

  __shared__ float Wl[64 * 64];
#pragma unroll
  for (int i = 0; i < 16; ++i) Wl[t + i * 256] = W[t + i * 256];
  __syncthreads();

  int l = lb * 256 + t;
  const float* xr = x + ((size_t)(n * SEQ + l) * HEADS + h) * HDIM;
  float xv[64];
#pragma unroll
  for (int i = 0; i < 16; ++i) {
    float4 v4 = *(const float4*)(xr + i * 4);
    xv[i * 4 + 0] = v4.x; xv[i * 4 + 1] = v4.y;
    xv[i * 4 + 2] = v4.z; xv[i * 4 + 3] = v4.w;
  }

  size_t slab = (size_t)(n * HEADS + h);
  if (tensor < 2) {
    unsigned short* outp = (tensor == 0 ? qp : kp) + (slab * SEQ + l) * HDIM;
    for (int e8 = 0; e8 < 8; ++e8) {
      float ye[8];
#pragma unroll
      for (int ei = 0; ei < 8; ++ei) {
        const float* wr = &Wl[(e8 * 8 + ei) * 64];
        float acc = 0.0f;
#pragma unroll
        for (int d4 = 0; d4 < 16; ++d4) {
          float4 w4 = *(const float4*)(wr + d4 * 4);
          acc += xv[d4 * 4 + 0] * w4.x + xv[d4 * 4 + 1] * w4.y +
                 xv[d4 * 4 + 2] * w4.z + xv[d4 * 4 + 3] * w4.w;
        }
        ye[ei] = acc * scale;
      }
      uint4 pk;
      pk.x = (unsigned)f2bf(ye[0]) | ((unsigned)f2bf(ye[1]) << 16);
      pk.y = (unsigned)f2bf(ye[2]) | ((unsigned)f2bf(ye[3]) << 16);
      pk.z = (unsigned)f2bf(ye[4]) | ((unsigned)f2bf(ye[5]) << 16);
      pk.w = (unsigned)f2bf(ye[6]) | ((unsigned)f2bf(ye[7]) << 16);
      *(uint4*)(outp + e8 * 8) = pk;
    }
  } else {
    unsigned short* outp = vt + slab * HDIM * SEQ + l;
    for (int e = 0; e < 64; ++e) {
      const float* wr = &Wl[e * 64];
      float acc = 0.0f;
#pragma unroll
      for (int d4 = 0; d4 < 16; ++d4) {
        float4 w4 = *(const float4*)(wr + d4 * 4);
        acc += xv[d4 * 4 + 0] * w4.x + xv[d4 * 4 + 1] * w4.y +
               xv[d4 * 4 + 2] * w4.z + xv[d4 * 4 + 3] * w4.w;
      }
      outp[(size_t)e * SEQ] = f2bf(acc);
    }
  }
}

// ---------------------------------------------------------------------------
// Flash attention v4: 32x32x16 MFMA, swapped QK^T, in-register softmax+P,
// permlane32_swap, double-buffered LDS staged via global_load_lds (width 16)
// with pre-swizzled global source (LDS dest linear).
// Block = 128 thr (2 waves); wave owns 32 q-rows; KVBLK = 64.
// ---------------------------------------------------------------------------
__global__ __launch_bounds__(128, 3) void attn_kernel(
    const unsigned short* __restrict__ qp, const unsigned short* __restrict__ kp,
    const unsigned short* __restrict__ vt, const float* __restrict__ biasf,
    const int* __restrict__ flags, unsigned short* __restrict__ ao) {
  int t = threadIdx.x;
  int w = t >> 6;
  int lane = t & 63;
  int l5 = lane & 31, hi = lane >> 5;
  int qw = blockIdx.x * 64 + w * 32;
  int h = blockIdx.y, n = blockIdx.z;
  size_t slab = (size_t)(n * HEADS + h);
  const unsigned short* Qb = qp + slab * SEQ * HDIM;
  const unsigned short* Kb = kp + slab * SEQ * HDIM;
  const unsigned short* Vb = vt + slab * (size_t)HDIM * SEQ;
  const float* biasp = biasf + n * SEQ;
  const int* flagp = flags + n * 32;

  __shared__ uint4 Kl[2][512];  // 16 KB: [64 k-rows][8 chunks], swizzled layout
  __shared__ uint4 Vl[2][512];  // 16 KB: [64 d-rows][8 chunks], swizzled layout

  int wu = __builtin_amdgcn_readfirstlane(w);

  // Q B-frags: lane holds Q[q=qw+l5][d = dstep*16 + hi*8 + j]
  short8 bq[4];
  {
    const unsigned short* qrow = Qb + (size_t)(qw + l5) * HDIM + hi * 8;
#pragma unroll
    for (int dstep = 0; dstep < 4; ++dstep)
      bq[dstep] = __builtin_bit_cast(short8, *(const uint4*)(qrow + dstep * 16));
  }

  f32x16 acc0 = {}, acc1 = {};
  float mrun = -1e30f, lrun = 0.0f;
  const int rsw = l5 & 7;

  // async stage of one K/V tile into buf: LDS slot s holds global chunk
  // (row = s>>3, c8 = (s&7)^(row&7))  == round-3's verified swizzle.
  auto STAGE = [&](int buf, int kb) {
#pragma unroll
    for (int i = 0; i < 4; ++i) {
      int idx = i * 128 + t;
      int row = idx >> 3;
      int c8 = (idx & 7) ^ (row & 7);
      const unsigned short* gk = Kb + (size_t)(kb + row) * HDIM + c8 * 8;
      const unsigned short* gv = Vb + (size_t)row * SEQ + kb + c8 * 8;
      __builtin_amdgcn_global_load_lds(
          (const __attribute__((address_space(1))) unsigned*)gk,
          (__attribute__((address_space(3))) unsigned*)&Kl[buf][i * 128 + wu * 64],
          16, 0, 0);
      __builtin_amdgcn_global_load_lds(
          (const __attribute__((address_space(1))) unsigned*)gv,
          (__attribute__((address_space(3))) unsigned*)&Vl[buf][i * 128 + wu * 64],
          16, 0, 0);
    }
  };

  STAGE(0, 0);
  int cur = 0;

  for (int kb = 0; kb < SEQ; kb += 64) {
    // barrier drains vmcnt(0): buf[cur] ready, and both waves are done
    // reading buf[cur^1] (previous iteration) before we overwrite it.
    __syncthreads();
    if (kb + 64 < SEQ) STAGE(cur ^ 1, kb + 64);

    // ---- QK^T: S^T[k][q]; s0 = k 0..31, s1 = k 32..63 ----
    f32x16 s0 = {}, s1 = {};
    __builtin_amdgcn_s_setprio(1);
#pragma unroll
    for (int dstep = 0; dstep < 4; ++dstep) {
      short8 kf0 = __builtin_bit_cast(short8, Kl[cur][l5 * 8 + ((dstep * 2 + hi) ^ rsw)]);
      short8 kf1 = __builtin_bit_cast(short8, Kl[cur][256 + l5 * 8 + ((dstep * 2 + hi) ^ rsw)]);
      s0 = __builtin_amdgcn_mfma_f32_32x32x16_bf16(kf0, bq[dstep], s0, 0, 0, 0);
      s1 = __builtin_amdgcn_mfma_f32_32x32x16_bf16(kf1, bq[dstep], s1, 0, 0, 0);
    }
    __builtin_amdgcn_s_setprio(0);

    // ---- optional mask bias (runtime-skipped when chunk fully unmasked) ----
    if (flagp[kb >> 6]) {
#pragma unroll
      for (int g = 0; g < 4; ++g) {
        f32x4 b0 = *(const f32x4*)(biasp + kb + g * 8 + hi * 4);
        f32x4 b1 = *(const f32x4*)(biasp + kb + 32 + g * 8 + hi * 4);
#pragma unroll
        for (int i = 0; i < 4; ++i) {
          s0[g * 4 + i] += b0[i];
          s1[g * 4 + i] += b1[i];
        }
      }
    }

    // ---- row max: in-lane tree over 32 + 1 shuffle ----
    float m0[8];
#pragma unroll
    for (int i = 0; i < 8; ++i)
      m0[i] = fmaxf(fmaxf(s0[i], s0[i + 8]), fmaxf(s1[i], s1[i + 8]));
    float rm = fmaxf(fmaxf(fmaxf(m0[0], m0[1]), fmaxf(m0[2], m0[3])),
                     fmaxf(fmaxf(m0[4], m0[5]), fmaxf(m0[6], m0[7])));
    rm = fmaxf(rm, __shfl_xor(rm, 32, 64));

    if (__any(rm > mrun)) {
      float mnew = fmaxf(mrun, rm);
      float rs = exp2f(mrun - mnew);
      mrun = mnew;
      lrun *= rs;
      acc0 = acc0 * rs;
      acc1 = acc1 * rs;
    }

    // ---- fused P = exp2(S-m) -> sum + bf16 pack (no p[32] array) ----
    float ps = 0.0f;
    unsigned wv[16];
#pragma unroll
    for (int i = 0; i < 8; ++i) {
      float p0 = exp2f(s0[2 * i] - mrun);
      float p1 = exp2f(s0[2 * i + 1] - mrun);
      ps += p0 + p1;
      wv[i] = cvtpk(p0, p1);
    }
#pragma unroll
    for (int i = 0; i < 8; ++i) {
      float p0 = exp2f(s1[2 * i] - mrun);
      float p1 = exp2f(s1[2 * i + 1] - mrun);
      ps += p0 + p1;
      wv[8 + i] = cvtpk(p0, p1);
    }
    ps += __shfl_xor(ps, 32, 64);
    lrun += ps;

    // ---- permlane32_swap into PV B-frags (verified in round 3) ----
    short8 pf[4];
#pragma unroll
    for (int kt = 0; kt < 2; ++kt) {
#pragma unroll
      for (int s = 0; s < 2; ++s) {
        unsigned a = wv[kt * 8 + s * 4 + 0], c = wv[kt * 8 + s * 4 + 2];
        unsigned b = wv[kt * 8 + s * 4 + 1], d = wv[kt * 8 + s * 4 + 3];
        swap32(a, c);
        swap32(b, d);
        uint4 u = {a, b, c, d};
        pf[kt * 2 + s] = __builtin_bit_cast(short8, u);
      }
    }

    // ---- PV: O^T[d][q] += V^T-frag x P-frag ----
    __builtin_amdgcn_s_setprio(1);
#pragma unroll
    for (int ks = 0; ks < 4; ++ks) {
      short8 v0 = __builtin_bit_cast(short8, Vl[cur][l5 * 8 + ((ks * 2 + hi) ^ rsw)]);
      short8 v1 = __builtin_bit_cast(short8, Vl[cur][256 + l5 * 8 + ((ks * 2 + hi) ^ rsw)]);
      acc0 = __builtin_amdgcn_mfma_f32_32x32x16_bf16(v0, pf[ks], acc0, 0, 0, 0);
      acc1 = __builtin_amdgcn_mfma_f32_32x32x16_bf16(v1, pf[ks], acc1, 0, 0, 0);
    }
    __builtin_amdgcn_s_setprio(0);
    cur ^= 1;
  }

  // ---- epilogue: lane holds O[q=qw+l5][d = db*32 + 8g + 4hi + i] ----
  float inv = 1.0f / lrun;
  unsigned short* obase = ao + ((size_t)(n * SEQ + qw + l5)) * EMB + h * HDIM + hi * 4;
#pragma unroll
  for (int g = 0; g < 4; ++g) {
    uint2 o0, o1;
    o0.x = cvtpk(acc0[g * 4 + 0] * inv, acc0[g * 4 + 1] * inv);
    o0.y = cvtpk(acc0[g * 4 + 2] * inv, acc0[g * 4 + 3] * inv);
    o1.x = cvtpk(acc1[g * 4 + 0] * inv, acc1[g * 4 + 1] * inv);
    o1.y = cvtpk(acc1[g * 4 + 2] * inv, acc1[g * 4 + 3] * inv);
    *(uint2*)(obase + g * 8) = o0;
    *(uint2*)(obase + 32 + g * 8) = o1;
  }
}

// ---------------------------------------------------------------------------
// Out-projection (unchanged, verified).
// ---------------------------------------------------------------------------
__global__ __launch_bounds__(256) void gemm_bt_kernel(
    const unsigned short* __restrict__ A, const unsigned short* __restrict__ B,
    const float* __restrict__ bias, float* __restrict__ Cm) {
  int t = threadIdx.x;
  int lane = t & 63, w = t >> 6;
  int lr = lane & 15, lg = lane >> 4;
  int m0 = blockIdx.y * 128, n0 = blockIdx.x * 64;
  int wr = w >> 1, wc = w & 1;

  __shared__ uint4 Al[1024];
  __shared__ uint4 Bl[512];

  f32x4 zero = {0.0f, 0.0f, 0.0f, 0.0f};
  f32x4 acc[4][2];
#pragma unroll
  for (int mt = 0; mt < 4; ++mt)
#pragma unroll
    for (int nt = 0; nt < 2; ++nt) acc[mt][nt] = zero;

  for (int kt = 0; kt < EMB; kt += 64) {
    __syncthreads();
#pragma unroll
    for (int s = 0; s < 4; ++s) {
      int c = t + s * 256;
      int row = c >> 3, c16 = c & 7;
      uint4 v = *(const uint4*)(A + (size_t)(m0 + row) * EMB + kt + c16 * 8);
      Al[(row * 8 + c16) ^ (row & 7)] = v;
    }
#pragma unroll
    for (int s = 0; s < 2; ++s) {
      int c = t + s * 256;
      int row = c >> 3, c16 = c & 7;
      uint4 v = *(const uint4*)(B + (size_t)(n0 + row) * EMB + kt + c16 * 8);
      Bl[(row * 8 + c16) ^ (row & 7)] = v;
    }
    __syncthreads();
#pragma unroll
    for (int kk = 0; kk < 2; ++kk) {
      short8 af[4], bfr[2];
#pragma unroll
      for (int mt = 0; mt < 4; ++mt) {
        int row = wr * 64 + mt * 16 + lr;
        af[mt] = __builtin_bit_cast(short8, Al[(row * 8 + kk * 4 + lg) ^ (row & 7)]);
      }
#pragma unroll
      for (int nt = 0; nt < 2; ++nt) {
        int row = wc * 32 + nt * 16 + lr;
        bfr[nt] = __builtin_bit_cast(short8, Bl[(row * 8 + kk * 4 + lg) ^ (row & 7)]);
      }
#pragma unroll
      for (int mt = 0; mt < 4; ++mt)
#pragma unroll
        for (int nt = 0; nt < 2; ++nt)
          acc[mt][nt] = __builtin_amdgcn_mfma_f32_16x16x32_bf16(af[mt], bfr[nt],
                                                                acc[mt][nt], 0, 0, 0);
    }
  }

#pragma unroll
  for (int nt = 0; nt < 2; ++nt) {
    int col = n0 + wc * 32 + nt * 16 + lr;
    float bv = bias[col];
#pragma unroll
    for (int mt = 0; mt < 4; ++mt) {
#pragma unroll
      for (int i = 0; i < 4; ++i) {
        int rowm = m0 + wr * 64 + mt * 16 + lg * 4 + i;
        Cm[(size_t)rowm * EMB + col] = acc[mt][nt][i] + bv;
      }
    }
  }
}

// ---------------------------------------------------------------------------
extern "C" void kernel_launch(void* const* d_in, const int* in_sizes, int n_in,
                              void* d_out, int out_size, void* d_ws, size_t ws_size,
                              hipStream_t stream) {
  const float* values = (const float*)d_in[0];
  const float* keys   = (const float*)d_in[1];
  const float* query  = (const float*)d_in[2];
  const int*   mask   = (const int*)d_in[3];
  const float* Wv     = (const float*)d_in[4];
  const float* Wk     = (const float*)d_in[5];
  const float* Wq     = (const float*)d_in[6];
  const float* Wo     = (const float*)d_in[7];
  const float* bo     = (const float*)d_in[8];
  float* out = (float*)d_out;

  const size_t slab = (size_t)NBATCH * HEADS * SEQ * HDIM;  // 4,194,304 elems
  unsigned short* qp  = (unsigned short*)d_ws;
  unsigned short* kp  = qp + slab;
  unsigned short* vt  = kp + slab;
  unsigned short* ao  = vt + slab;
  unsigned short* wob = ao + slab;
  float* biasf = (float*)(wob + (size_t)EMB * EMB);
  int* flags = (int*)(biasf + NBATCH * SEQ);

  float qscale = 1.4426950408889634f / 32.0f;

  prep_kernel<<<dim3(1029), 256, 0, stream>>>(Wo, wob, mask, biasf, flags);
  proj_kernel<<<dim3(SEQ / 256, HEADS, 6), 256, 0, stream>>>(
      query, keys, values, Wq, Wk, Wv, qp, kp, vt, qscale);
  attn_kernel<<<dim3(SEQ / 64, HEADS, NBATCH), 128, 0, stream>>>(qp, kp, vt, biasf,
                                                                 flags, ao);
  gemm_bt_kernel<<<dim3(EMB / 64, (NBATCH * SEQ) / 128), 256, 0, stream>>>(ao, wob, bo, out);
}